// Round 1
// baseline (873.879 us; speedup 1.0000x reference)
//
#include <hip/hip_runtime.h>

// GCN 2-layer forward on MI355X (gfx950).
// Pipeline: count deg -> dinv -> CSR(scan+fill) -> GEMM1(bf16 MFMA, fused f32->bf16 cast)
//           -> agg1 (wave/node, no atomics) -> relu+W2 transform -> agg2 -> out.

#define NN 100000
#define NE 1600000
#define INC 768
#define HID 256
#define NCLS 8

typedef short bf16x8 __attribute__((ext_vector_type(8)));   // 8 bf16 in 4 VGPRs (guide-verified operand type)
typedef float f32x4 __attribute__((ext_vector_type(4)));

__device__ __forceinline__ unsigned short f2bf(float f) {
  unsigned int u = __float_as_uint(f);
  unsigned int r = (u + 0x7FFFu + ((u >> 16) & 1u)) >> 16;  // RNE
  return (unsigned short)r;
}
__device__ __forceinline__ float bf2f(unsigned short h) {
  return __uint_as_float(((unsigned int)h) << 16);
}

// ---------- degree / norm ----------
__global__ __launch_bounds__(256) void k_zero(int* __restrict__ cnt) {
  int i = blockIdx.x * 256 + threadIdx.x;
  if (i < NN) cnt[i] = 0;
}
__global__ __launch_bounds__(256) void k_count(const int* __restrict__ ei, int* __restrict__ cnt) {
  int e = blockIdx.x * 256 + threadIdx.x;
  if (e < NE) atomicAdd(&cnt[ei[NE + e]], 1);  // col = targets
}
__global__ __launch_bounds__(256) void k_dinv(const int* __restrict__ cnt, float* __restrict__ dinv) {
  int i = blockIdx.x * 256 + threadIdx.x;
  if (i < NN) dinv[i] = rsqrtf((float)cnt[i] + 1.0f);  // +1 self-loop
}

// ---------- CSR: exclusive scan (single block) + fill ----------
__global__ __launch_bounds__(1024) void k_scan(const int* __restrict__ cnt, int* __restrict__ rowptr,
                                               int* __restrict__ cursor) {
  __shared__ int s[1024];
  __shared__ int s_run;
  int tid = threadIdx.x;
  if (tid == 0) s_run = 0;
  __syncthreads();
  for (int base = 0; base < NN; base += 1024) {
    int i = base + tid;
    int v = (i < NN) ? cnt[i] : 0;
    s[tid] = v;
    __syncthreads();
    for (int off = 1; off < 1024; off <<= 1) {
      int t2 = (tid >= off) ? s[tid - off] : 0;
      __syncthreads();
      s[tid] += t2;
      __syncthreads();
    }
    int run = s_run;
    int excl = s[tid] - v;
    if (i < NN) { rowptr[i] = run + excl; cursor[i] = run + excl; }
    __syncthreads();
    if (tid == 1023) s_run = run + s[1023];
    __syncthreads();
  }
  if (threadIdx.x == 0) rowptr[NN] = s_run;
}
__global__ __launch_bounds__(256) void k_fill(const int* __restrict__ ei, int* __restrict__ cursor,
                                              int* __restrict__ srcidx) {
  int e = blockIdx.x * 256 + threadIdx.x;
  if (e >= NE) return;
  int r = ei[e];         // source
  int c = ei[NE + e];    // target
  int pos = atomicAdd(&cursor[c], 1);
  srcidx[pos] = r;
}

// ---------- W1 transpose+cast: w1t[n][k] = bf16(W1[k][n]) ----------
__global__ __launch_bounds__(256) void k_w1t(const float* __restrict__ W1, unsigned short* __restrict__ w1t) {
  int t = blockIdx.x * 256 + threadIdx.x;
  if (t >= INC * HID) return;
  int k = t / HID, n = t % HID;
  w1t[n * INC + k] = f2bf(W1[t]);
}

// ---------- GEMM1: h1[100000][256] (bf16) = x[100000][768] @ W1 ----------
// 128x256 tile, BK=64, 512 threads = 8 waves (2x4), wave = 64x64 (4x4 frags of 16x16x32).
// LDS rows are 128B: XOR-swizzle seg^(row&7) -> conflict-free b128 reads.
__global__ __launch_bounds__(512) void k_gemm1(const float* __restrict__ x,
                                               const unsigned short* __restrict__ w1t,
                                               unsigned short* __restrict__ h1) {
  __shared__ unsigned short As[128 * 64];   // 16 KB  [row][k]
  __shared__ unsigned short Bs[256 * 64];   // 32 KB  [col][k]  (W1^T tile)
  const int tid = threadIdx.x;
  const int lane = tid & 63;
  const int wid = tid >> 6;
  const int wm = wid >> 2;        // 0..1
  const int wn = wid & 3;         // 0..3
  const long bm = blockIdx.x;

  f32x4 acc[4][4];
#pragma unroll
  for (int m = 0; m < 4; m++)
#pragma unroll
    for (int n = 0; n < 4; n++) acc[m][n] = (f32x4){0.f, 0.f, 0.f, 0.f};

  for (int kt = 0; kt < INC; kt += 64) {
    // stage A: 1024 16B-chunks, fp32 -> bf16 in regs
    uint4 ra[2];
    uint4 rb[4];
#pragma unroll
    for (int p = 0; p < 2; p++) {
      int idx = tid + p * 512;
      int r = idx >> 3, s7 = idx & 7;
      long arow = bm * 128 + r;
      if (arow > NN - 1) arow = NN - 1;  // clamp tail (782*128 > 100000)
      const float* ga = x + arow * INC + kt + s7 * 8;
      float4 f0 = *(const float4*)ga;
      float4 f1 = *(const float4*)(ga + 4);
      union { unsigned short us[8]; uint4 v; } u;
      u.us[0] = f2bf(f0.x); u.us[1] = f2bf(f0.y); u.us[2] = f2bf(f0.z); u.us[3] = f2bf(f0.w);
      u.us[4] = f2bf(f1.x); u.us[5] = f2bf(f1.y); u.us[6] = f2bf(f1.z); u.us[7] = f2bf(f1.w);
      ra[p] = u.v;
    }
#pragma unroll
    for (int p = 0; p < 4; p++) {
      int idx = tid + p * 512;
      int r = idx >> 3, s7 = idx & 7;
      rb[p] = *(const uint4*)(w1t + (long)r * INC + kt + s7 * 8);
    }
    __syncthreads();
#pragma unroll
    for (int p = 0; p < 2; p++) {
      int idx = tid + p * 512;
      int r = idx >> 3, s7 = idx & 7;
      int off = (r << 7) | ((s7 ^ (r & 7)) << 4);
      *(uint4*)((char*)As + off) = ra[p];
    }
#pragma unroll
    for (int p = 0; p < 4; p++) {
      int idx = tid + p * 512;
      int r = idx >> 3, s7 = idx & 7;
      int off = (r << 7) | ((s7 ^ (r & 7)) << 4);
      *(uint4*)((char*)Bs + off) = rb[p];
    }
    __syncthreads();
#pragma unroll
    for (int half = 0; half < 2; half++) {
      bf16x8 af[4], bff[4];
      int j = (half << 2) + (lane >> 4);
#pragma unroll
      for (int m = 0; m < 4; m++) {
        int row = wm * 64 + m * 16 + (lane & 15);
        int off = (row << 7) | ((j ^ (row & 7)) << 4);
        af[m] = *(const bf16x8*)((const char*)As + off);
      }
#pragma unroll
      for (int n = 0; n < 4; n++) {
        int row = wn * 64 + n * 16 + (lane & 15);
        int off = (row << 7) | ((j ^ (row & 7)) << 4);
        bff[n] = *(const bf16x8*)((const char*)Bs + off);
      }
#pragma unroll
      for (int m = 0; m < 4; m++)
#pragma unroll
        for (int n = 0; n < 4; n++)
          acc[m][n] = __builtin_amdgcn_mfma_f32_16x16x32_bf16(af[m], bff[n], acc[m][n], 0, 0, 0);
    }
    __syncthreads();
  }
  // epilogue: C/D layout col=lane&15, row=(lane>>4)*4+r  (m89-verified)
#pragma unroll
  for (int m = 0; m < 4; m++) {
    int grow0 = (int)(bm * 128) + wm * 64 + m * 16 + ((lane >> 4) << 2);
#pragma unroll
    for (int n = 0; n < 4; n++) {
      int gcol = wn * 64 + n * 16 + (lane & 15);
#pragma unroll
      for (int r = 0; r < 4; r++) {
        int grow = grow0 + r;
        if (grow < NN) h1[(long)grow * HID + gcol] = f2bf(acc[m][n][r]);
      }
    }
  }
}

// ---------- agg1: wave per node, lane owns 4 channels ----------
__global__ __launch_bounds__(256) void k_agg1(const unsigned short* __restrict__ h1,
                                              const float* __restrict__ dinv,
                                              const int* __restrict__ rowptr,
                                              const int* __restrict__ srcidx,
                                              float* __restrict__ agg1) {
  int w = (int)((blockIdx.x * 256 + threadIdx.x) >> 6);
  int lane = threadIdx.x & 63;
  if (w >= NN) return;
  float di = dinv[w];
  int c4 = lane << 2;
  ushort4 hv = *(const ushort4*)(h1 + (long)w * HID + c4);
  float self = di * di;
  float a0 = self * bf2f(hv.x), a1 = self * bf2f(hv.y);
  float a2 = self * bf2f(hv.z), a3 = self * bf2f(hv.w);
  int e0 = rowptr[w], e1 = rowptr[w + 1];
  for (int e = e0; e < e1; e++) {
    int src = srcidx[e];
    float ws = di * dinv[src];
    ushort4 h = *(const ushort4*)(h1 + (long)src * HID + c4);
    a0 += ws * bf2f(h.x); a1 += ws * bf2f(h.y);
    a2 += ws * bf2f(h.z); a3 += ws * bf2f(h.w);
  }
  float4 o; o.x = a0; o.y = a1; o.z = a2; o.w = a3;
  *(float4*)(agg1 + (long)w * HID + c4) = o;
}

// ---------- layer2 transform: h2 = relu(agg1 + b1) @ W2 ----------
__global__ __launch_bounds__(256) void k_l2(const float* __restrict__ agg1,
                                            const float* __restrict__ b1,
                                            const float* __restrict__ W2,
                                            float* __restrict__ h2) {
  __shared__ float w2s[HID * NCLS];
  __shared__ float b1s[HID];
  int tid = threadIdx.x;
#pragma unroll
  for (int i = tid; i < HID * NCLS; i += 256) w2s[i] = W2[i];
  b1s[tid] = b1[tid];
  __syncthreads();
  long t = (long)blockIdx.x * 256 + tid;
  long i = t >> 3;
  int c = (int)(t & 7);
  if (i >= NN) return;
  const float4* ap = (const float4*)(agg1 + i * HID);
  float s = 0.f;
#pragma unroll 4
  for (int k4 = 0; k4 < HID / 4; k4++) {
    float4 a = ap[k4];
    int k = k4 * 4;
    float v0 = a.x + b1s[k + 0]; v0 = v0 > 0.f ? v0 : 0.f;
    float v1 = a.y + b1s[k + 1]; v1 = v1 > 0.f ? v1 : 0.f;
    float v2 = a.z + b1s[k + 2]; v2 = v2 > 0.f ? v2 : 0.f;
    float v3 = a.w + b1s[k + 3]; v3 = v3 > 0.f ? v3 : 0.f;
    s += v0 * w2s[(k + 0) * NCLS + c] + v1 * w2s[(k + 1) * NCLS + c] +
         v2 * w2s[(k + 2) * NCLS + c] + v3 * w2s[(k + 3) * NCLS + c];
  }
  h2[i * NCLS + c] = s;
}

// ---------- agg2 + bias -> out ----------
__global__ __launch_bounds__(256) void k_agg2(const float* __restrict__ h2,
                                              const float* __restrict__ dinv,
                                              const int* __restrict__ rowptr,
                                              const int* __restrict__ srcidx,
                                              const float* __restrict__ b2,
                                              float* __restrict__ out) {
  long t = (long)blockIdx.x * 256 + threadIdx.x;
  long i = t >> 3;
  int c = (int)(t & 7);
  if (i >= NN) return;
  float di = dinv[i];
  float s = di * di * h2[i * NCLS + c];
  int e0 = rowptr[i], e1 = rowptr[i + 1];
  for (int e = e0; e < e1; e++) {
    int src = srcidx[e];
    s += di * dinv[src] * h2[src * NCLS + c];
  }
  out[i * NCLS + c] = s + b2[c];
}

extern "C" void kernel_launch(void* const* d_in, const int* in_sizes, int n_in,
                              void* d_out, int out_size, void* d_ws, size_t ws_size,
                              hipStream_t stream) {
  (void)in_sizes; (void)n_in; (void)out_size; (void)ws_size;
  const float* x  = (const float*)d_in[0];
  const int*   ei = (const int*)d_in[1];
  const float* W1 = (const float*)d_in[2];
  const float* b1 = (const float*)d_in[3];
  const float* W2 = (const float*)d_in[4];
  const float* b2 = (const float*)d_in[5];
  float* out = (float*)d_out;
  char* ws = (char*)d_ws;

  // ws layout (all 16B aligned), total ~165.2 MB
  unsigned short* h1   = (unsigned short*)(ws + 0L);            // 51,200,000
  float* agg1          = (float*)(ws + 51200000L);              // 102,400,000
  float* h2            = (float*)(ws + 153600000L);             // 3,200,000
  float* dinv          = (float*)(ws + 156800000L);             // 400,000
  int*   cnt           = (int*)(ws + 157200000L);               // 400,000
  int*   rowptr        = (int*)(ws + 157600000L);               // 400,004 (+pad)
  int*   cursor        = (int*)(ws + 158000128L);               // 400,000
  int*   srcidx        = (int*)(ws + 158400128L);               // 6,400,000
  unsigned short* w1t  = (unsigned short*)(ws + 164800128L);    // 393,216

  k_zero<<<(NN + 255) / 256, 256, 0, stream>>>(cnt);
  k_count<<<(NE + 255) / 256, 256, 0, stream>>>(ei, cnt);
  k_dinv<<<(NN + 255) / 256, 256, 0, stream>>>(cnt, dinv);
  k_scan<<<1, 1024, 0, stream>>>(cnt, rowptr, cursor);
  k_fill<<<(NE + 255) / 256, 256, 0, stream>>>(ei, cursor, srcidx);
  k_w1t<<<(INC * HID + 255) / 256, 256, 0, stream>>>(W1, w1t);
  k_gemm1<<<782, 512, 0, stream>>>(x, w1t, h1);
  k_agg1<<<(NN * 64) / 256, 256, 0, stream>>>(h1, dinv, rowptr, srcidx, agg1);
  k_l2<<<(NN * NCLS) / 256, 256, 0, stream>>>(agg1, b1, W2, h2);
  k_agg2<<<(NN * NCLS) / 256, 256, 0, stream>>>(h2, dinv, rowptr, srcidx, b2, out);
}

// Round 2
// 556.072 us; speedup vs baseline: 1.5715x; 1.5715x over previous
//
#include <hip/hip_runtime.h>

// GCN 2-layer forward on MI355X (gfx950).
// R2: multi-block scan (was single-block, est. 200-400us), agg1 edge-loop
//     unroll x4 with precomputed per-edge (src,norm) packing, relu+W2 fused
//     into agg1 epilogue (k_l2 eliminated, -204MB traffic).

#define NN 100000
#define NE 1600000
#define INC 768
#define HID 256
#define NCLS 8
#define NBLK 391  // ceil(NN/256)

typedef short bf16x8 __attribute__((ext_vector_type(8)));
typedef float f32x4 __attribute__((ext_vector_type(4)));

__device__ __forceinline__ unsigned short f2bf(float f) {
  unsigned int u = __float_as_uint(f);
  unsigned int r = (u + 0x7FFFu + ((u >> 16) & 1u)) >> 16;  // RNE
  return (unsigned short)r;
}
__device__ __forceinline__ float bf2f(unsigned short h) {
  return __uint_as_float(((unsigned int)h) << 16);
}

// ---------- degree / norm ----------
__global__ __launch_bounds__(256) void k_zero(int* __restrict__ cnt) {
  int i = blockIdx.x * 256 + threadIdx.x;
  if (i < NN) cnt[i] = 0;
}
__global__ __launch_bounds__(256) void k_count(const int* __restrict__ ei, int* __restrict__ cnt) {
  int e = blockIdx.x * 256 + threadIdx.x;
  if (e < NE) atomicAdd(&cnt[ei[NE + e]], 1);  // col = targets
}
__global__ __launch_bounds__(256) void k_dinv(const int* __restrict__ cnt, float* __restrict__ dinv) {
  int i = blockIdx.x * 256 + threadIdx.x;
  if (i < NN) dinv[i] = rsqrtf((float)cnt[i] + 1.0f);  // +1 self-loop
}

// ---------- CSR: 3-phase exclusive scan ----------
__global__ __launch_bounds__(256) void k_scan1(const int* __restrict__ cnt, int* __restrict__ bsum) {
  __shared__ int s[256];
  int i = blockIdx.x * 256 + threadIdx.x;
  s[threadIdx.x] = (i < NN) ? cnt[i] : 0;
  __syncthreads();
#pragma unroll
  for (int off = 128; off > 0; off >>= 1) {
    if (threadIdx.x < off) s[threadIdx.x] += s[threadIdx.x + off];
    __syncthreads();
  }
  if (threadIdx.x == 0) bsum[blockIdx.x] = s[0];
}
__global__ __launch_bounds__(512) void k_scan2(const int* __restrict__ bsum, int* __restrict__ boff,
                                               int* __restrict__ rowptr) {
  __shared__ int s[512];
  int tid = threadIdx.x;
  int v = (tid < NBLK) ? bsum[tid] : 0;
  s[tid] = v;
  __syncthreads();
#pragma unroll
  for (int off = 1; off < 512; off <<= 1) {
    int t = (tid >= off) ? s[tid - off] : 0;
    __syncthreads();
    s[tid] += t;
    __syncthreads();
  }
  if (tid < NBLK) boff[tid] = s[tid] - v;
  if (tid == NBLK - 1) rowptr[NN] = s[tid];
}
__global__ __launch_bounds__(256) void k_scan3(const int* __restrict__ cnt, const int* __restrict__ boff,
                                               int* __restrict__ rowptr, int* __restrict__ cursor) {
  __shared__ int s[256];
  int i = blockIdx.x * 256 + threadIdx.x;
  int v = (i < NN) ? cnt[i] : 0;
  s[threadIdx.x] = v;
  __syncthreads();
#pragma unroll
  for (int off = 1; off < 256; off <<= 1) {
    int t = (threadIdx.x >= off) ? s[threadIdx.x - off] : 0;
    __syncthreads();
    s[threadIdx.x] += t;
    __syncthreads();
  }
  if (i < NN) {
    int e = boff[blockIdx.x] + s[threadIdx.x] - v;
    rowptr[i] = e;
    cursor[i] = e;
  }
}
// fill: per-edge packed (src, dinv[src]*dinv[col])
__global__ __launch_bounds__(256) void k_fill(const int* __restrict__ ei, const float* __restrict__ dinv,
                                              int* __restrict__ cursor, int2* __restrict__ epk) {
  int e = blockIdx.x * 256 + threadIdx.x;
  if (e >= NE) return;
  int r = ei[e];         // source
  int c = ei[NE + e];    // target
  float w = dinv[r] * dinv[c];
  int pos = atomicAdd(&cursor[c], 1);
  epk[pos] = make_int2(r, __float_as_int(w));
}

// ---------- W1 transpose+cast ----------
__global__ __launch_bounds__(256) void k_w1t(const float* __restrict__ W1, unsigned short* __restrict__ w1t) {
  int t = blockIdx.x * 256 + threadIdx.x;
  if (t >= INC * HID) return;
  int k = t / HID, n = t % HID;
  w1t[n * INC + k] = f2bf(W1[t]);
}

// ---------- GEMM1: h1[NN][256] (bf16) = x @ W1 ----------
__global__ __launch_bounds__(512) void k_gemm1(const float* __restrict__ x,
                                               const unsigned short* __restrict__ w1t,
                                               unsigned short* __restrict__ h1) {
  __shared__ unsigned short As[128 * 64];
  __shared__ unsigned short Bs[256 * 64];
  const int tid = threadIdx.x;
  const int lane = tid & 63;
  const int wid = tid >> 6;
  const int wm = wid >> 2;
  const int wn = wid & 3;
  const long bm = blockIdx.x;

  f32x4 acc[4][4];
#pragma unroll
  for (int m = 0; m < 4; m++)
#pragma unroll
    for (int n = 0; n < 4; n++) acc[m][n] = (f32x4){0.f, 0.f, 0.f, 0.f};

  for (int kt = 0; kt < INC; kt += 64) {
    uint4 ra[2];
    uint4 rb[4];
#pragma unroll
    for (int p = 0; p < 2; p++) {
      int idx = tid + p * 512;
      int r = idx >> 3, s7 = idx & 7;
      long arow = bm * 128 + r;
      if (arow > NN - 1) arow = NN - 1;
      const float* ga = x + arow * INC + kt + s7 * 8;
      float4 f0 = *(const float4*)ga;
      float4 f1 = *(const float4*)(ga + 4);
      union { unsigned short us[8]; uint4 v; } u;
      u.us[0] = f2bf(f0.x); u.us[1] = f2bf(f0.y); u.us[2] = f2bf(f0.z); u.us[3] = f2bf(f0.w);
      u.us[4] = f2bf(f1.x); u.us[5] = f2bf(f1.y); u.us[6] = f2bf(f1.z); u.us[7] = f2bf(f1.w);
      ra[p] = u.v;
    }
#pragma unroll
    for (int p = 0; p < 4; p++) {
      int idx = tid + p * 512;
      int r = idx >> 3, s7 = idx & 7;
      rb[p] = *(const uint4*)(w1t + (long)r * INC + kt + s7 * 8);
    }
    __syncthreads();
#pragma unroll
    for (int p = 0; p < 2; p++) {
      int idx = tid + p * 512;
      int r = idx >> 3, s7 = idx & 7;
      int off = (r << 7) | ((s7 ^ (r & 7)) << 4);
      *(uint4*)((char*)As + off) = ra[p];
    }
#pragma unroll
    for (int p = 0; p < 4; p++) {
      int idx = tid + p * 512;
      int r = idx >> 3, s7 = idx & 7;
      int off = (r << 7) | ((s7 ^ (r & 7)) << 4);
      *(uint4*)((char*)Bs + off) = rb[p];
    }
    __syncthreads();
#pragma unroll
    for (int half = 0; half < 2; half++) {
      bf16x8 af[4], bff[4];
      int j = (half << 2) + (lane >> 4);
#pragma unroll
      for (int m = 0; m < 4; m++) {
        int row = wm * 64 + m * 16 + (lane & 15);
        int off = (row << 7) | ((j ^ (row & 7)) << 4);
        af[m] = *(const bf16x8*)((const char*)As + off);
      }
#pragma unroll
      for (int n = 0; n < 4; n++) {
        int row = wn * 64 + n * 16 + (lane & 15);
        int off = (row << 7) | ((j ^ (row & 7)) << 4);
        bff[n] = *(const bf16x8*)((const char*)Bs + off);
      }
#pragma unroll
      for (int m = 0; m < 4; m++)
#pragma unroll
        for (int n = 0; n < 4; n++)
          acc[m][n] = __builtin_amdgcn_mfma_f32_16x16x32_bf16(af[m], bff[n], acc[m][n], 0, 0, 0);
    }
    __syncthreads();
  }
#pragma unroll
  for (int m = 0; m < 4; m++) {
    int grow0 = (int)(bm * 128) + wm * 64 + m * 16 + ((lane >> 4) << 2);
#pragma unroll
    for (int n = 0; n < 4; n++) {
      int gcol = wn * 64 + n * 16 + (lane & 15);
#pragma unroll
      for (int r = 0; r < 4; r++) {
        int grow = grow0 + r;
        if (grow < NN) h1[(long)grow * HID + gcol] = f2bf(acc[m][n][r]);
      }
    }
  }
}

// ---------- agg1 fused with relu+b1+W2: h2 = relu(agg(h1)+b1) @ W2 ----------
// wave per node; lane owns 4 channels; edge loop unrolled x4 (4 gathers in flight).
__global__ __launch_bounds__(256) void k_agg1(const unsigned short* __restrict__ h1,
                                              const float* __restrict__ dinv,
                                              const int* __restrict__ rowptr,
                                              const int2* __restrict__ epk,
                                              const float* __restrict__ b1,
                                              const float* __restrict__ W2,
                                              float* __restrict__ h2) {
  int w = (int)((blockIdx.x * 256 + threadIdx.x) >> 6);
  int lane = threadIdx.x & 63;
  if (w >= NN) return;
  float di = dinv[w];
  int c4 = lane << 2;
  ushort4 hv = *(const ushort4*)(h1 + (long)w * HID + c4);
  float self = di * di;
  float a0 = self * bf2f(hv.x), a1 = self * bf2f(hv.y);
  float a2 = self * bf2f(hv.z), a3 = self * bf2f(hv.w);
  int e0 = rowptr[w], e1 = rowptr[w + 1];
  int e = e0;
  for (; e + 4 <= e1; e += 4) {
    int2 q0 = epk[e], q1 = epk[e + 1], q2 = epk[e + 2], q3 = epk[e + 3];
    ushort4 g0 = *(const ushort4*)(h1 + (long)q0.x * HID + c4);
    ushort4 g1 = *(const ushort4*)(h1 + (long)q1.x * HID + c4);
    ushort4 g2 = *(const ushort4*)(h1 + (long)q2.x * HID + c4);
    ushort4 g3 = *(const ushort4*)(h1 + (long)q3.x * HID + c4);
    float w0 = __int_as_float(q0.y), w1 = __int_as_float(q1.y);
    float w2 = __int_as_float(q2.y), w3 = __int_as_float(q3.y);
    a0 += w0 * bf2f(g0.x) + w1 * bf2f(g1.x) + w2 * bf2f(g2.x) + w3 * bf2f(g3.x);
    a1 += w0 * bf2f(g0.y) + w1 * bf2f(g1.y) + w2 * bf2f(g2.y) + w3 * bf2f(g3.y);
    a2 += w0 * bf2f(g0.z) + w1 * bf2f(g1.z) + w2 * bf2f(g2.z) + w3 * bf2f(g3.z);
    a3 += w0 * bf2f(g0.w) + w1 * bf2f(g1.w) + w2 * bf2f(g2.w) + w3 * bf2f(g3.w);
  }
  for (; e < e1; e++) {
    int2 q = epk[e];
    float ws = __int_as_float(q.y);
    ushort4 g = *(const ushort4*)(h1 + (long)q.x * HID + c4);
    a0 += ws * bf2f(g.x); a1 += ws * bf2f(g.y);
    a2 += ws * bf2f(g.z); a3 += ws * bf2f(g.w);
  }
  // relu(a + b1) then per-lane 4ch x 8cls partials
  float4 bv = *(const float4*)(b1 + c4);
  float v0 = a0 + bv.x; v0 = v0 > 0.f ? v0 : 0.f;
  float v1 = a1 + bv.y; v1 = v1 > 0.f ? v1 : 0.f;
  float v2 = a2 + bv.z; v2 = v2 > 0.f ? v2 : 0.f;
  float v3 = a3 + bv.w; v3 = v3 > 0.f ? v3 : 0.f;
  const float4* wp = (const float4*)(W2 + ((long)c4 << 3));  // rows c4..c4+3, 8 cols
  float4 r0a = wp[0], r0b = wp[1], r1a = wp[2], r1b = wp[3];
  float4 r2a = wp[4], r2b = wp[5], r3a = wp[6], r3b = wp[7];
  float p[8];
  p[0] = v0 * r0a.x + v1 * r1a.x + v2 * r2a.x + v3 * r3a.x;
  p[1] = v0 * r0a.y + v1 * r1a.y + v2 * r2a.y + v3 * r3a.y;
  p[2] = v0 * r0a.z + v1 * r1a.z + v2 * r2a.z + v3 * r3a.z;
  p[3] = v0 * r0a.w + v1 * r1a.w + v2 * r2a.w + v3 * r3a.w;
  p[4] = v0 * r0b.x + v1 * r1b.x + v2 * r2b.x + v3 * r3b.x;
  p[5] = v0 * r0b.y + v1 * r1b.y + v2 * r2b.y + v3 * r3b.y;
  p[6] = v0 * r0b.z + v1 * r1b.z + v2 * r2b.z + v3 * r3b.z;
  p[7] = v0 * r0b.w + v1 * r1b.w + v2 * r2b.w + v3 * r3b.w;
#pragma unroll
  for (int c = 0; c < 8; c++)
#pragma unroll
    for (int off = 1; off < 64; off <<= 1) p[c] += __shfl_xor(p[c], off, 64);
  if (lane < 8) {
    float o = p[0];
    o = (lane == 1) ? p[1] : o;
    o = (lane == 2) ? p[2] : o;
    o = (lane == 3) ? p[3] : o;
    o = (lane == 4) ? p[4] : o;
    o = (lane == 5) ? p[5] : o;
    o = (lane == 6) ? p[6] : o;
    o = (lane == 7) ? p[7] : o;
    h2[(long)w * NCLS + lane] = o;
  }
}

// ---------- agg2 + bias -> out ----------
__global__ __launch_bounds__(256) void k_agg2(const float* __restrict__ h2,
                                              const float* __restrict__ dinv,
                                              const int* __restrict__ rowptr,
                                              const int2* __restrict__ epk,
                                              const float* __restrict__ b2,
                                              float* __restrict__ out) {
  long t = (long)blockIdx.x * 256 + threadIdx.x;
  long i = t >> 3;
  int c = (int)(t & 7);
  if (i >= NN) return;
  float di = dinv[i];
  float s = di * di * h2[i * NCLS + c];
  int e0 = rowptr[i], e1 = rowptr[i + 1];
  int e = e0;
  for (; e + 4 <= e1; e += 4) {
    int2 q0 = epk[e], q1 = epk[e + 1], q2 = epk[e + 2], q3 = epk[e + 3];
    float g0 = h2[(long)q0.x * NCLS + c], g1 = h2[(long)q1.x * NCLS + c];
    float g2 = h2[(long)q2.x * NCLS + c], g3 = h2[(long)q3.x * NCLS + c];
    s += __int_as_float(q0.y) * g0 + __int_as_float(q1.y) * g1 +
         __int_as_float(q2.y) * g2 + __int_as_float(q3.y) * g3;
  }
  for (; e < e1; e++) {
    int2 q = epk[e];
    s += __int_as_float(q.y) * h2[(long)q.x * NCLS + c];
  }
  out[i * NCLS + c] = s + b2[c];
}

extern "C" void kernel_launch(void* const* d_in, const int* in_sizes, int n_in,
                              void* d_out, int out_size, void* d_ws, size_t ws_size,
                              hipStream_t stream) {
  (void)in_sizes; (void)n_in; (void)out_size; (void)ws_size;
  const float* x  = (const float*)d_in[0];
  const int*   ei = (const int*)d_in[1];
  const float* W1 = (const float*)d_in[2];
  const float* b1 = (const float*)d_in[3];
  const float* W2 = (const float*)d_in[4];
  const float* b2 = (const float*)d_in[5];
  float* out = (float*)d_out;
  char* ws = (char*)d_ws;

  unsigned short* h1   = (unsigned short*)(ws + 0L);          // 51,200,000
  float* h2            = (float*)(ws + 51200000L);            // 3,200,000
  float* dinv          = (float*)(ws + 54400000L);            // 400,000
  int*   cnt           = (int*)(ws + 54800000L);              // 400,000
  int*   rowptr        = (int*)(ws + 55200000L);              // 400,004 (+pad)
  int*   cursor        = (int*)(ws + 55600128L);              // 400,000
  int2*  epk           = (int2*)(ws + 56000128L);             // 12,800,000
  unsigned short* w1t  = (unsigned short*)(ws + 68800128L);   // 393,216
  int*   bsum          = (int*)(ws + 69195008L);              // 1,564
  int*   boff          = (int*)(ws + 69196608L);              // 1,564

  k_zero<<<(NN + 255) / 256, 256, 0, stream>>>(cnt);
  k_count<<<(NE + 255) / 256, 256, 0, stream>>>(ei, cnt);
  k_dinv<<<(NN + 255) / 256, 256, 0, stream>>>(cnt, dinv);
  k_scan1<<<NBLK, 256, 0, stream>>>(cnt, bsum);
  k_scan2<<<1, 512, 0, stream>>>(bsum, boff, rowptr);
  k_scan3<<<NBLK, 256, 0, stream>>>(cnt, boff, rowptr, cursor);
  k_fill<<<(NE + 255) / 256, 256, 0, stream>>>(ei, dinv, cursor, epk);
  k_w1t<<<(INC * HID + 255) / 256, 256, 0, stream>>>(W1, w1t);
  k_gemm1<<<782, 512, 0, stream>>>(x, w1t, h1);
  k_agg1<<<(NN * 64 + 255) / 256, 256, 0, stream>>>(h1, dinv, rowptr, epk, b1, W2, h2);
  k_agg2<<<(NN * NCLS + 255) / 256, 256, 0, stream>>>(h2, dinv, rowptr, epk, b2, out);
}

// Round 3
// 461.090 us; speedup vs baseline: 1.8952x; 1.2060x over previous
//
#include <hip/hip_runtime.h>

// GCN 2-layer forward on MI355X (gfx950).
// R3: gemm1 software-pipelined (reg-prefetch t+1, consumed at next LDS-write)
//     + LDS-staged coalesced epilogue (WRITE_SIZE 178MB -> ~55MB).

#define NN 100000
#define NE 1600000
#define INC 768
#define HID 256
#define NCLS 8
#define NBLK 391  // ceil(NN/256)

typedef short bf16x8 __attribute__((ext_vector_type(8)));
typedef float f32x4 __attribute__((ext_vector_type(4)));

__device__ __forceinline__ unsigned short f2bf(float f) {
  unsigned int u = __float_as_uint(f);
  unsigned int r = (u + 0x7FFFu + ((u >> 16) & 1u)) >> 16;  // RNE
  return (unsigned short)r;
}
__device__ __forceinline__ float bf2f(unsigned short h) {
  return __uint_as_float(((unsigned int)h) << 16);
}

// ---------- degree / norm ----------
__global__ __launch_bounds__(256) void k_zero(int* __restrict__ cnt) {
  int i = blockIdx.x * 256 + threadIdx.x;
  if (i < NN) cnt[i] = 0;
}
__global__ __launch_bounds__(256) void k_count(const int* __restrict__ ei, int* __restrict__ cnt) {
  int e = blockIdx.x * 256 + threadIdx.x;
  if (e < NE) atomicAdd(&cnt[ei[NE + e]], 1);  // col = targets
}
__global__ __launch_bounds__(256) void k_dinv(const int* __restrict__ cnt, float* __restrict__ dinv) {
  int i = blockIdx.x * 256 + threadIdx.x;
  if (i < NN) dinv[i] = rsqrtf((float)cnt[i] + 1.0f);  // +1 self-loop
}

// ---------- CSR: 3-phase exclusive scan ----------
__global__ __launch_bounds__(256) void k_scan1(const int* __restrict__ cnt, int* __restrict__ bsum) {
  __shared__ int s[256];
  int i = blockIdx.x * 256 + threadIdx.x;
  s[threadIdx.x] = (i < NN) ? cnt[i] : 0;
  __syncthreads();
#pragma unroll
  for (int off = 128; off > 0; off >>= 1) {
    if (threadIdx.x < off) s[threadIdx.x] += s[threadIdx.x + off];
    __syncthreads();
  }
  if (threadIdx.x == 0) bsum[blockIdx.x] = s[0];
}
__global__ __launch_bounds__(512) void k_scan2(const int* __restrict__ bsum, int* __restrict__ boff,
                                               int* __restrict__ rowptr) {
  __shared__ int s[512];
  int tid = threadIdx.x;
  int v = (tid < NBLK) ? bsum[tid] : 0;
  s[tid] = v;
  __syncthreads();
#pragma unroll
  for (int off = 1; off < 512; off <<= 1) {
    int t = (tid >= off) ? s[tid - off] : 0;
    __syncthreads();
    s[tid] += t;
    __syncthreads();
  }
  if (tid < NBLK) boff[tid] = s[tid] - v;
  if (tid == NBLK - 1) rowptr[NN] = s[tid];
}
__global__ __launch_bounds__(256) void k_scan3(const int* __restrict__ cnt, const int* __restrict__ boff,
                                               int* __restrict__ rowptr, int* __restrict__ cursor) {
  __shared__ int s[256];
  int i = blockIdx.x * 256 + threadIdx.x;
  int v = (i < NN) ? cnt[i] : 0;
  s[threadIdx.x] = v;
  __syncthreads();
#pragma unroll
  for (int off = 1; off < 256; off <<= 1) {
    int t = (threadIdx.x >= off) ? s[threadIdx.x - off] : 0;
    __syncthreads();
    s[threadIdx.x] += t;
    __syncthreads();
  }
  if (i < NN) {
    int e = boff[blockIdx.x] + s[threadIdx.x] - v;
    rowptr[i] = e;
    cursor[i] = e;
  }
}
// fill: per-edge packed (src, dinv[src]*dinv[col])
__global__ __launch_bounds__(256) void k_fill(const int* __restrict__ ei, const float* __restrict__ dinv,
                                              int* __restrict__ cursor, int2* __restrict__ epk) {
  int e = blockIdx.x * 256 + threadIdx.x;
  if (e >= NE) return;
  int r = ei[e];         // source
  int c = ei[NE + e];    // target
  float w = dinv[r] * dinv[c];
  int pos = atomicAdd(&cursor[c], 1);
  epk[pos] = make_int2(r, __float_as_int(w));
}

// ---------- W1 transpose+cast ----------
__global__ __launch_bounds__(256) void k_w1t(const float* __restrict__ W1, unsigned short* __restrict__ w1t) {
  int t = blockIdx.x * 256 + threadIdx.x;
  if (t >= INC * HID) return;
  int k = t / HID, n = t % HID;
  w1t[n * INC + k] = f2bf(W1[t]);
}

// ---------- GEMM1: h1[NN][256] (bf16) = x @ W1 ----------
// 128x256 tile, BK=64, 8 waves. Pipelined: regs for tile t+1 loaded while
// computing tile t; LDS single-buffered (write | barrier | load t+1 + MFMA | barrier).
__global__ __launch_bounds__(512) void k_gemm1(const float* __restrict__ x,
                                               const unsigned short* __restrict__ w1t,
                                               unsigned short* __restrict__ h1) {
  __shared__ char smem[49152];
  unsigned short* As = (unsigned short*)smem;            // 128*64*2 = 16 KB
  unsigned short* Bs = (unsigned short*)(smem + 16384);  // 256*64*2 = 32 KB
  const int tid = threadIdx.x;
  const int lane = tid & 63;
  const int wid = tid >> 6;
  const int wm = wid >> 2;
  const int wn = wid & 3;
  const long bm = blockIdx.x;

  // staging geometry (fixed per thread)
  const int ar0 = tid >> 3, as7 = tid & 7;          // A: p=0 row, seg
  const int ar1 = (tid + 512) >> 3;                 // A: p=1 row (same seg)
  long arow0 = bm * 128 + ar0; if (arow0 > NN - 1) arow0 = NN - 1;
  long arow1 = bm * 128 + ar1; if (arow1 > NN - 1) arow1 = NN - 1;
  const float* gA0 = x + arow0 * INC + as7 * 8;
  const float* gA1 = x + arow1 * INC + as7 * 8;
  const int aoff0 = (ar0 << 7) | ((as7 ^ (ar0 & 7)) << 4);
  const int aoff1 = (ar1 << 7) | ((as7 ^ (ar1 & 7)) << 4);

  f32x4 acc[4][4];
#pragma unroll
  for (int m = 0; m < 4; m++)
#pragma unroll
    for (int n = 0; n < 4; n++) acc[m][n] = (f32x4){0.f, 0.f, 0.f, 0.f};

  float4 fa00, fa01, fa10, fa11;  // A prefetch (fp32)
  uint4 rb0, rb1, rb2, rb3;       // B prefetch (bf16 x8)

#define LOAD_AB(KT)                                                        \
  do {                                                                     \
    fa00 = *(const float4*)(gA0 + (KT));                                   \
    fa01 = *(const float4*)(gA0 + (KT) + 4);                               \
    fa10 = *(const float4*)(gA1 + (KT));                                   \
    fa11 = *(const float4*)(gA1 + (KT) + 4);                               \
    rb0 = *(const uint4*)(w1t + (long)(tid >> 3) * INC + (KT) + (tid & 7) * 8);            \
    rb1 = *(const uint4*)(w1t + (long)((tid + 512) >> 3) * INC + (KT) + (tid & 7) * 8);    \
    rb2 = *(const uint4*)(w1t + (long)((tid + 1024) >> 3) * INC + (KT) + (tid & 7) * 8);   \
    rb3 = *(const uint4*)(w1t + (long)((tid + 1536) >> 3) * INC + (KT) + (tid & 7) * 8);   \
  } while (0)

  LOAD_AB(0);

  for (int kt = 0; kt < INC; kt += 64) {
    // ---- write phase (regs from previous load) ----
    {
      union { unsigned short us[8]; uint4 v; } u;
      u.us[0] = f2bf(fa00.x); u.us[1] = f2bf(fa00.y); u.us[2] = f2bf(fa00.z); u.us[3] = f2bf(fa00.w);
      u.us[4] = f2bf(fa01.x); u.us[5] = f2bf(fa01.y); u.us[6] = f2bf(fa01.z); u.us[7] = f2bf(fa01.w);
      *(uint4*)((char*)As + aoff0) = u.v;
      u.us[0] = f2bf(fa10.x); u.us[1] = f2bf(fa10.y); u.us[2] = f2bf(fa10.z); u.us[3] = f2bf(fa10.w);
      u.us[4] = f2bf(fa11.x); u.us[5] = f2bf(fa11.y); u.us[6] = f2bf(fa11.z); u.us[7] = f2bf(fa11.w);
      *(uint4*)((char*)As + aoff1) = u.v;
    }
    {
      int r0 = tid >> 3, s7 = tid & 7;
      *(uint4*)((char*)Bs + ((r0 << 7) | ((s7 ^ (r0 & 7)) << 4))) = rb0;
      int r1 = (tid + 512) >> 3;
      *(uint4*)((char*)Bs + ((r1 << 7) | ((s7 ^ (r1 & 7)) << 4))) = rb1;
      int r2 = (tid + 1024) >> 3;
      *(uint4*)((char*)Bs + ((r2 << 7) | ((s7 ^ (r2 & 7)) << 4))) = rb2;
      int r3 = (tid + 1536) >> 3;
      *(uint4*)((char*)Bs + ((r3 << 7) | ((s7 ^ (r3 & 7)) << 4))) = rb3;
    }
    __syncthreads();
    // ---- issue next tile's global loads (latency hides under MFMA) ----
    if (kt + 64 < INC) LOAD_AB(kt + 64);
    // ---- compute phase ----
#pragma unroll
    for (int half = 0; half < 2; half++) {
      bf16x8 af[4], bff[4];
      int j = (half << 2) + (lane >> 4);
#pragma unroll
      for (int m = 0; m < 4; m++) {
        int row = wm * 64 + m * 16 + (lane & 15);
        int off = (row << 7) | ((j ^ (row & 7)) << 4);
        af[m] = *(const bf16x8*)((const char*)As + off);
      }
#pragma unroll
      for (int n = 0; n < 4; n++) {
        int row = wn * 64 + n * 16 + (lane & 15);
        int off = (row << 7) | ((j ^ (row & 7)) << 4);
        bff[n] = *(const bf16x8*)((const char*)Bs + off);
      }
#pragma unroll
      for (int m = 0; m < 4; m++)
#pragma unroll
        for (int n = 0; n < 4; n++)
          acc[m][n] = __builtin_amdgcn_mfma_f32_16x16x32_bf16(af[m], bff[n], acc[m][n], 0, 0, 0);
    }
    __syncthreads();
  }
#undef LOAD_AB

  // ---- epilogue: stage 64-row half-tiles in LDS, copy out full rows ----
  unsigned short* Os = (unsigned short*)smem;  // [64][264] shorts = 33 KB (reuse As+Bs)
#pragma unroll
  for (int chunk = 0; chunk < 2; chunk++) {
    if (wm == chunk) {
#pragma unroll
      for (int m = 0; m < 4; m++)
#pragma unroll
        for (int n = 0; n < 4; n++) {
          int lrow = m * 16 + ((lane >> 4) << 2);
          int lcol = wn * 64 + n * 16 + (lane & 15);
#pragma unroll
          for (int r = 0; r < 4; r++)
            Os[(lrow + r) * 264 + lcol] = f2bf(acc[m][n][r]);
        }
    }
    __syncthreads();
    {
      int r = tid >> 3, s = tid & 7;
      long grow = bm * 128 + chunk * 64 + r;
      if (grow < NN) {
        unsigned short* dst = h1 + grow * HID;
#pragma unroll
        for (int i = 0; i < 4; i++) {
          int seg = s + i * 8;
          *(uint4*)(dst + seg * 8) = *(const uint4*)((const char*)Os + (long)r * 528 + seg * 16);
        }
      }
    }
    __syncthreads();
  }
}

// ---------- agg1 fused with relu+b1+W2: h2 = relu(agg(h1)+b1) @ W2 ----------
__global__ __launch_bounds__(256) void k_agg1(const unsigned short* __restrict__ h1,
                                              const float* __restrict__ dinv,
                                              const int* __restrict__ rowptr,
                                              const int2* __restrict__ epk,
                                              const float* __restrict__ b1,
                                              const float* __restrict__ W2,
                                              float* __restrict__ h2) {
  int w = (int)((blockIdx.x * 256 + threadIdx.x) >> 6);
  int lane = threadIdx.x & 63;
  if (w >= NN) return;
  float di = dinv[w];
  int c4 = lane << 2;
  ushort4 hv = *(const ushort4*)(h1 + (long)w * HID + c4);
  float self = di * di;
  float a0 = self * bf2f(hv.x), a1 = self * bf2f(hv.y);
  float a2 = self * bf2f(hv.z), a3 = self * bf2f(hv.w);
  int e0 = rowptr[w], e1 = rowptr[w + 1];
  int e = e0;
  for (; e + 4 <= e1; e += 4) {
    int2 q0 = epk[e], q1 = epk[e + 1], q2 = epk[e + 2], q3 = epk[e + 3];
    ushort4 g0 = *(const ushort4*)(h1 + (long)q0.x * HID + c4);
    ushort4 g1 = *(const ushort4*)(h1 + (long)q1.x * HID + c4);
    ushort4 g2 = *(const ushort4*)(h1 + (long)q2.x * HID + c4);
    ushort4 g3 = *(const ushort4*)(h1 + (long)q3.x * HID + c4);
    float w0 = __int_as_float(q0.y), w1 = __int_as_float(q1.y);
    float w2 = __int_as_float(q2.y), w3 = __int_as_float(q3.y);
    a0 += w0 * bf2f(g0.x) + w1 * bf2f(g1.x) + w2 * bf2f(g2.x) + w3 * bf2f(g3.x);
    a1 += w0 * bf2f(g0.y) + w1 * bf2f(g1.y) + w2 * bf2f(g2.y) + w3 * bf2f(g3.y);
    a2 += w0 * bf2f(g0.z) + w1 * bf2f(g1.z) + w2 * bf2f(g2.z) + w3 * bf2f(g3.z);
    a3 += w0 * bf2f(g0.w) + w1 * bf2f(g1.w) + w2 * bf2f(g2.w) + w3 * bf2f(g3.w);
  }
  for (; e < e1; e++) {
    int2 q = epk[e];
    float ws = __int_as_float(q.y);
    ushort4 g = *(const ushort4*)(h1 + (long)q.x * HID + c4);
    a0 += ws * bf2f(g.x); a1 += ws * bf2f(g.y);
    a2 += ws * bf2f(g.z); a3 += ws * bf2f(g.w);
  }
  float4 bv = *(const float4*)(b1 + c4);
  float v0 = a0 + bv.x; v0 = v0 > 0.f ? v0 : 0.f;
  float v1 = a1 + bv.y; v1 = v1 > 0.f ? v1 : 0.f;
  float v2 = a2 + bv.z; v2 = v2 > 0.f ? v2 : 0.f;
  float v3 = a3 + bv.w; v3 = v3 > 0.f ? v3 : 0.f;
  const float4* wp = (const float4*)(W2 + ((long)c4 << 3));
  float4 r0a = wp[0], r0b = wp[1], r1a = wp[2], r1b = wp[3];
  float4 r2a = wp[4], r2b = wp[5], r3a = wp[6], r3b = wp[7];
  float p[8];
  p[0] = v0 * r0a.x + v1 * r1a.x + v2 * r2a.x + v3 * r3a.x;
  p[1] = v0 * r0a.y + v1 * r1a.y + v2 * r2a.y + v3 * r3a.y;
  p[2] = v0 * r0a.z + v1 * r1a.z + v2 * r2a.z + v3 * r3a.z;
  p[3] = v0 * r0a.w + v1 * r1a.w + v2 * r2a.w + v3 * r3a.w;
  p[4] = v0 * r0b.x + v1 * r1b.x + v2 * r2b.x + v3 * r3b.x;
  p[5] = v0 * r0b.y + v1 * r1b.y + v2 * r2b.y + v3 * r3b.y;
  p[6] = v0 * r0b.z + v1 * r1b.z + v2 * r2b.z + v3 * r3b.z;
  p[7] = v0 * r0b.w + v1 * r1b.w + v2 * r2b.w + v3 * r3b.w;
#pragma unroll
  for (int c = 0; c < 8; c++)
#pragma unroll
    for (int off = 1; off < 64; off <<= 1) p[c] += __shfl_xor(p[c], off, 64);
  if (lane < 8) {
    float o = p[0];
    o = (lane == 1) ? p[1] : o;
    o = (lane == 2) ? p[2] : o;
    o = (lane == 3) ? p[3] : o;
    o = (lane == 4) ? p[4] : o;
    o = (lane == 5) ? p[5] : o;
    o = (lane == 6) ? p[6] : o;
    o = (lane == 7) ? p[7] : o;
    h2[(long)w * NCLS + lane] = o;
  }
}

// ---------- agg2 + bias -> out ----------
__global__ __launch_bounds__(256) void k_agg2(const float* __restrict__ h2,
                                              const float* __restrict__ dinv,
                                              const int* __restrict__ rowptr,
                                              const int2* __restrict__ epk,
                                              const float* __restrict__ b2,
                                              float* __restrict__ out) {
  long t = (long)blockIdx.x * 256 + threadIdx.x;
  long i = t >> 3;
  int c = (int)(t & 7);
  if (i >= NN) return;
  float di = dinv[i];
  float s = di * di * h2[i * NCLS + c];
  int e0 = rowptr[i], e1 = rowptr[i + 1];
  int e = e0;
  for (; e + 4 <= e1; e += 4) {
    int2 q0 = epk[e], q1 = epk[e + 1], q2 = epk[e + 2], q3 = epk[e + 3];
    float g0 = h2[(long)q0.x * NCLS + c], g1 = h2[(long)q1.x * NCLS + c];
    float g2 = h2[(long)q2.x * NCLS + c], g3 = h2[(long)q3.x * NCLS + c];
    s += __int_as_float(q0.y) * g0 + __int_as_float(q1.y) * g1 +
         __int_as_float(q2.y) * g2 + __int_as_float(q3.y) * g3;
  }
  for (; e < e1; e++) {
    int2 q = epk[e];
    s += __int_as_float(q.y) * h2[(long)q.x * NCLS + c];
  }
  out[i * NCLS + c] = s + b2[c];
}

extern "C" void kernel_launch(void* const* d_in, const int* in_sizes, int n_in,
                              void* d_out, int out_size, void* d_ws, size_t ws_size,
                              hipStream_t stream) {
  (void)in_sizes; (void)n_in; (void)out_size; (void)ws_size;
  const float* x  = (const float*)d_in[0];
  const int*   ei = (const int*)d_in[1];
  const float* W1 = (const float*)d_in[2];
  const float* b1 = (const float*)d_in[3];
  const float* W2 = (const float*)d_in[4];
  const float* b2 = (const float*)d_in[5];
  float* out = (float*)d_out;
  char* ws = (char*)d_ws;

  unsigned short* h1   = (unsigned short*)(ws + 0L);          // 51,200,000
  float* h2            = (float*)(ws + 51200000L);            // 3,200,000
  float* dinv          = (float*)(ws + 54400000L);            // 400,000
  int*   cnt           = (int*)(ws + 54800000L);              // 400,000
  int*   rowptr        = (int*)(ws + 55200000L);              // 400,004 (+pad)
  int*   cursor        = (int*)(ws + 55600128L);              // 400,000
  int2*  epk           = (int2*)(ws + 56000128L);             // 12,800,000
  unsigned short* w1t  = (unsigned short*)(ws + 68800128L);   // 393,216
  int*   bsum          = (int*)(ws + 69195008L);              // 1,564
  int*   boff          = (int*)(ws + 69196608L);              // 1,564

  k_zero<<<(NN + 255) / 256, 256, 0, stream>>>(cnt);
  k_count<<<(NE + 255) / 256, 256, 0, stream>>>(ei, cnt);
  k_dinv<<<(NN + 255) / 256, 256, 0, stream>>>(cnt, dinv);
  k_scan1<<<NBLK, 256, 0, stream>>>(cnt, bsum);
  k_scan2<<<1, 512, 0, stream>>>(bsum, boff, rowptr);
  k_scan3<<<NBLK, 256, 0, stream>>>(cnt, boff, rowptr, cursor);
  k_fill<<<(NE + 255) / 256, 256, 0, stream>>>(ei, dinv, cursor, epk);
  k_w1t<<<(INC * HID + 255) / 256, 256, 0, stream>>>(W1, w1t);
  k_gemm1<<<782, 512, 0, stream>>>(x, w1t, h1);
  k_agg1<<<(NN * 64 + 255) / 256, 256, 0, stream>>>(h1, dinv, rowptr, epk, b1, W2, h2);
  k_agg2<<<(NN * NCLS + 255) / 256, 256, 0, stream>>>(h2, dinv, rowptr, epk, b2, out);
}